// Round 3
// baseline (2062.134 us; speedup 1.0000x reference)
//
#include <hip/hip_runtime.h>
#include <cstdint>

typedef __attribute__((ext_vector_type(8))) short short8;
typedef __attribute__((ext_vector_type(4))) float f32x4;

__device__ __forceinline__ ushort f2bf(float x){
    uint32_t u = __float_as_uint(x);
    u = (u + 0x7FFFu + ((u >> 16) & 1u)) >> 16;
    return (ushort)u;
}

// ---------------- kernel 1: fp32 -> bf16 weight conversion ----------------
__global__ void k_conv(const float* __restrict__ W1, const float* __restrict__ W2,
                       const float* __restrict__ Emb,
                       ushort* __restrict__ W1b, ushort* __restrict__ W2b,
                       ushort* __restrict__ Eb){
    int i = blockIdx.x * 256 + threadIdx.x;   // grid 256 -> 65536
    W1b[i] = f2bf(W1[i]);
    W2b[i] = f2bf(W2[i]);
    Eb[i]  = f2bf(Emb[i]);
}

// -------- kernel 2: proj[v][h] = sum_e embed[v,e]*W_in[h,e]  (fp32) -------
__global__ void k_proj(const float* __restrict__ emb, const float* __restrict__ Win,
                       float* __restrict__ proj){
    __shared__ __align__(16) float se[256];
    int v = blockIdx.x, h = threadIdx.x;
    se[h] = emb[v*256 + h];
    __syncthreads();
    const float* wr = Win + h*256;
    float a0=0.f,a1=0.f,a2=0.f,a3=0.f;
    #pragma unroll
    for (int e = 0; e < 256; e += 4){
        float4 w = *(const float4*)(wr + e);
        a0 = fmaf(w.x, se[e+0], a0);
        a1 = fmaf(w.y, se[e+1], a1);
        a2 = fmaf(w.z, se[e+2], a2);
        a3 = fmaf(w.w, se[e+3], a3);
    }
    proj[v*256 + h] = (a0+a1)+(a2+a3);
}

// ---------------- kernel 3: ESN recurrence, fp32, W pinned in VGPRs -------
// 128 blocks (one per batch row) x 512 threads (8 waves, 2/SIMD).
// thread t: c = t&7 (k-octant), rg = t>>3 (0..63); owns rows {4rg+q, q=0..3}
// x cols [32c, 32c+32). In-wave octet reduction via shfl_xor(1,2,4);
// lanes c<4 finalize row 4rg+c (distinct banks, contiguous hs store).
// W chunks loaded pre-rotated by c so LDS h-reads are conflict-free and all
// register arrays are compile-time indexed. Empty "+v" asm pins W in VGPRs
// (prevents the L2 re-fetch rematerialization seen in rounds 1-2).
__global__ __launch_bounds__(512, 2) void k_recur(const int* __restrict__ idx,
        const float* __restrict__ W, const float* __restrict__ proj,
        ushort* __restrict__ hs){
    __shared__ __align__(16) float s_h[2][256];
    __shared__ int s_idx[2048];
    const int tid = threadIdx.x;
    const int b   = blockIdx.x;
    const int c   = tid & 7;
    const int rg  = tid >> 3;

    for (int i = tid; i < 2048; i += 512) s_idx[i] = idx[b*2048 + i];
    if (tid < 256) s_h[0][tid] = 0.f;

    // W[4rg+q][32c .. 32c+31], chunk j holds rotated chunk (j+c)&7
    float4 w4[4][8];
    #pragma unroll
    for (int q = 0; q < 4; ++q){
        const float* wr = W + (4*rg + q)*256 + c*32;
        #pragma unroll
        for (int j = 0; j < 8; ++j)
            w4[q][j] = *(const float4*)(wr + 4*((j + c) & 7));
    }
    // pin: make each W value opaque so it MUST stay live in a VGPR
    #pragma unroll
    for (int q = 0; q < 4; ++q){
        #pragma unroll
        for (int j = 0; j < 8; ++j){
            asm volatile("" : "+v"(w4[q][j].x), "+v"(w4[q][j].y),
                             "+v"(w4[q][j].z), "+v"(w4[q][j].w));
        }
    }
    __syncthreads();

    const int myrow = 4*rg + c;               // finalized row when c<4
    float h_prev = 0.f;
    ushort* hrow = hs + (size_t)b * 2048 * 256;
    int cur = 0;
    for (int t = 0; t < 2048; ++t){
        int token = s_idx[t];
        float u = 0.f;
        if (c < 4) u = proj[token*256 + myrow];    // issued early, consumed late

        const float4* h4 = (const float4*)(&s_h[cur][c*32]);
        f32x4 a0 = {0.f,0.f,0.f,0.f}, a1 = a0, a2 = a0, a3 = a0;
        #pragma unroll
        for (int j = 0; j < 8; ++j){
            float4 hv = h4[(j + c) & 7];           // LDS addr runtime, regs static
            float4 w0 = w4[0][j], w1 = w4[1][j], w2 = w4[2][j], w3 = w4[3][j];
            a0[0]=fmaf(w0.x,hv.x,a0[0]); a0[1]=fmaf(w0.y,hv.y,a0[1]);
            a0[2]=fmaf(w0.z,hv.z,a0[2]); a0[3]=fmaf(w0.w,hv.w,a0[3]);
            a1[0]=fmaf(w1.x,hv.x,a1[0]); a1[1]=fmaf(w1.y,hv.y,a1[1]);
            a1[2]=fmaf(w1.z,hv.z,a1[2]); a1[3]=fmaf(w1.w,hv.w,a1[3]);
            a2[0]=fmaf(w2.x,hv.x,a2[0]); a2[1]=fmaf(w2.y,hv.y,a2[1]);
            a2[2]=fmaf(w2.z,hv.z,a2[2]); a2[3]=fmaf(w2.w,hv.w,a2[3]);
            a3[0]=fmaf(w3.x,hv.x,a3[0]); a3[1]=fmaf(w3.y,hv.y,a3[1]);
            a3[2]=fmaf(w3.z,hv.z,a3[2]); a3[3]=fmaf(w3.w,hv.w,a3[3]);
        }
        float s0 = (a0[0]+a0[1])+(a0[2]+a0[3]);
        float s1 = (a1[0]+a1[1])+(a1[2]+a1[3]);
        float s2 = (a2[0]+a2[1])+(a2[2]+a2[3]);
        float s3 = (a3[0]+a3[1])+(a3[2]+a3[3]);
        s0 += __shfl_xor(s0,1); s0 += __shfl_xor(s0,2); s0 += __shfl_xor(s0,4);
        s1 += __shfl_xor(s1,1); s1 += __shfl_xor(s1,2); s1 += __shfl_xor(s1,4);
        s2 += __shfl_xor(s2,1); s2 += __shfl_xor(s2,2); s2 += __shfl_xor(s2,4);
        s3 += __shfl_xor(s3,1); s3 += __shfl_xor(s3,2); s3 += __shfl_xor(s3,4);
        if (c < 4){
            float pre = (c==0 ? s0 : c==1 ? s1 : c==2 ? s2 : s3) + u;
            pre = fminf(20.f, fmaxf(-20.f, pre));
            float e  = __expf(2.f*pre);
            float th = 1.f - __fdividef(2.f, e + 1.f);
            float hn = 0.7f*h_prev + 0.3f*th;
            h_prev = hn;
            s_h[cur^1][myrow] = hn;
            hrow[(size_t)t*256 + myrow] = f2bf(hn);
        }
        // LDS-only barrier: do NOT drain vmcnt (the hs store floats free)
        asm volatile("s_waitcnt lgkmcnt(0)\n\ts_barrier" ::: "memory");
        cur ^= 1;
    }
}

// ---------------- kernel 4: fused readout MLP + LN + lm_head --------------
// per block: 128 rows of BT. 512 threads = 8 waves, wave owns 16 rows.
// GEMM1 (swapped, D[e,m]) -> gelu -> A1_lds[m][e]
// GEMM2 (swapped, D[e2,m]) -> LN over e2 -> y_lds[m][e2] (overwrites A1)
// GEMM3 (unswapped, D[m,v]) -> fp32 out
__global__ __launch_bounds__(512) void k_readout(
        const ushort* __restrict__ hs,
        const ushort* __restrict__ W1b, const ushort* __restrict__ W2b,
        const ushort* __restrict__ Eb,
        const float* __restrict__ b1, const float* __restrict__ b2,
        const float* __restrict__ gamma, const float* __restrict__ beta,
        float* __restrict__ out){
    __shared__ __align__(16) char w_lds[65536];   // staged weight half: 128 rows x 256 bf16
    __shared__ __align__(16) char a_lds[65536];   // A1 / y tile: 128 rows x 256 bf16

    const int tid  = threadIdx.x;
    const int wid  = tid >> 6;
    const int lane = tid & 63;
    const int lr   = lane & 15;
    const int lg   = lane >> 4;
    const size_t m0 = (size_t)blockIdx.x * 128;
    const int ml   = wid*16 + lr;                 // this lane's m-row (local)

    // stage a 128x256 bf16 weight half into w_lds, XOR-swizzled
    auto stage = [&](const ushort* src){
        #pragma unroll
        for (int i = 0; i < 8; ++i){
            int off = (i*512 + tid) * 16;
            uint4 v = *(const uint4*)((const char*)src + off);
            int row = off >> 9;
            *(uint4*)(w_lds + (off ^ ((row & 7) << 4))) = v;
        }
    };
    // A-fragment of staged weight, tile n, k-chunk k0
    auto wfrag = [&](int n, int k0) -> short8 {
        int row  = n*16 + lr;
        int addr = (row << 9) + k0*64 + lg*16;
        addr ^= (row & 7) << 4;
        return __builtin_bit_cast(short8, *(const uint4*)(w_lds + addr));
    };
    // fragment of a_lds at own m-row, k-chunk k0
    auto afrag = [&](int k0) -> short8 {
        int addr = (ml << 9) + k0*64 + lg*16;
        addr ^= (ml & 7) << 4;
        return __builtin_bit_cast(short8, *(const uint4*)(a_lds + addr));
    };
    // write 4 consecutive e-values (8B) into a_lds[ml][ecol..ecol+3]
    auto awrite = [&](int ecol, f32x4 v){
        ushort4 pk;
        pk.x = f2bf(v[0]); pk.y = f2bf(v[1]); pk.z = f2bf(v[2]); pk.w = f2bf(v[3]);
        int addr = (ml << 9) + ecol*2;
        addr ^= (ml & 7) << 4;
        *(ushort4*)(a_lds + addr) = pk;
    };

    // ---- hs fragments straight from global (16B/lane, reused both halves) ----
    short8 hb[8];
    {
        const char* p = (const char*)(hs + (m0 + ml)*256) + lg*16;
        #pragma unroll
        for (int k0 = 0; k0 < 8; ++k0)
            hb[k0] = __builtin_bit_cast(short8, *(const uint4*)(p + k0*64));
    }

    // ================= GEMM1: A1 = gelu(hs @ W1.T + b1) =================
    #pragma unroll
    for (int h = 0; h < 2; ++h){
        __syncthreads();
        stage(W1b + h*128*256);
        __syncthreads();
        #pragma unroll
        for (int n = 0; n < 8; ++n){
            int eb = h*128 + n*16;
            float4 bi = *(const float4*)(b1 + eb + lg*4);
            f32x4 acc = {bi.x, bi.y, bi.z, bi.w};
            #pragma unroll
            for (int k0 = 0; k0 < 8; ++k0)
                acc = __builtin_amdgcn_mfma_f32_16x16x32_bf16(wfrag(n,k0), hb[k0], acc, 0,0,0);
            f32x4 g;
            #pragma unroll
            for (int q = 0; q < 4; ++q){
                float x = acc[q];
                g[q] = 0.5f*x*(1.f + erff(x*0.70710678118654752440f));
            }
            awrite(eb + lg*4, g);
        }
    }

    // ================= GEMM2: o = A1 @ W2.T + b2 =================
    short8 ab[8];
    __syncthreads();
    #pragma unroll
    for (int k0 = 0; k0 < 8; ++k0) ab[k0] = afrag(k0);
    f32x4 oacc[16];
    #pragma unroll
    for (int h = 0; h < 2; ++h){
        __syncthreads();
        stage(W2b + h*128*256);
        __syncthreads();
        #pragma unroll
        for (int n = 0; n < 8; ++n){
            int eb = h*128 + n*16;
            float4 bi = *(const float4*)(b2 + eb + lg*4);
            f32x4 acc = {bi.x, bi.y, bi.z, bi.w};
            #pragma unroll
            for (int k0 = 0; k0 < 8; ++k0)
                acc = __builtin_amdgcn_mfma_f32_16x16x32_bf16(wfrag(n,k0), ab[k0], acc, 0,0,0);
            oacc[h*8+n] = acc;
        }
    }

    // ================= LayerNorm over e2 (row dim of swapped D2) =================
    {
        float sum = 0.f, ss = 0.f;
        #pragma unroll
        for (int i = 0; i < 16; ++i){
            #pragma unroll
            for (int q = 0; q < 4; ++q){ float x = oacc[i][q]; sum += x; ss += x*x; }
        }
        sum += __shfl_xor(sum, 16); ss += __shfl_xor(ss, 16);
        sum += __shfl_xor(sum, 32); ss += __shfl_xor(ss, 32);
        float mu   = sum * (1.f/256.f);
        float var  = ss * (1.f/256.f) - mu*mu;
        float rstd = rsqrtf(var + 1e-5f);
        #pragma unroll
        for (int i = 0; i < 16; ++i){
            int ecol = (i >> 3)*128 + (i & 7)*16 + lg*4;
            float4 g4 = *(const float4*)(gamma + ecol);
            float4 t4 = *(const float4*)(beta + ecol);
            f32x4 y;
            y[0] = (oacc[i][0]-mu)*rstd*g4.x + t4.x;
            y[1] = (oacc[i][1]-mu)*rstd*g4.y + t4.y;
            y[2] = (oacc[i][2]-mu)*rstd*g4.z + t4.z;
            y[3] = (oacc[i][3]-mu)*rstd*g4.w + t4.w;
            awrite(ecol, y);
        }
    }

    // ================= GEMM3: logits = y @ embed.T (unswapped) =================
    __syncthreads();
    #pragma unroll
    for (int k0 = 0; k0 < 8; ++k0) ab[k0] = afrag(k0);   // y fragments
    #pragma unroll
    for (int h = 0; h < 2; ++h){
        __syncthreads();
        stage(Eb + h*128*256);
        __syncthreads();
        #pragma unroll
        for (int n = 0; n < 8; ++n){
            f32x4 acc = {0.f,0.f,0.f,0.f};
            #pragma unroll
            for (int k0 = 0; k0 < 8; ++k0)
                acc = __builtin_amdgcn_mfma_f32_16x16x32_bf16(ab[k0], wfrag(n,k0), acc, 0,0,0);
            int v = h*128 + n*16 + lr;
            float* op = out + (m0 + wid*16 + lg*4)*256 + v;
            op[0]   = acc[0];
            op[256] = acc[1];
            op[512] = acc[2];
            op[768] = acc[3];
        }
    }
}

// --------------------------------------------------------------------------
extern "C" void kernel_launch(void* const* d_in, const int* in_sizes, int n_in,
                              void* d_out, int out_size, void* d_ws, size_t ws_size,
                              hipStream_t stream){
    const int*   idx   = (const int*)d_in[0];
    const float* embed = (const float*)d_in[1];
    const float* W_in  = (const float*)d_in[2];
    const float* W     = (const float*)d_in[3];
    const float* W1    = (const float*)d_in[4];
    const float* b1    = (const float*)d_in[5];
    const float* W2    = (const float*)d_in[6];
    const float* b2    = (const float*)d_in[7];
    const float* gamma = (const float*)d_in[8];
    const float* beta  = (const float*)d_in[9];

    char* ws = (char*)d_ws;
    float*  proj = (float*)ws;                    // 256 KB fp32
    ushort* W1b  = (ushort*)(ws + 262144);        // 128 KB bf16
    ushort* W2b  = (ushort*)(ws + 393216);        // 128 KB
    ushort* Eb   = (ushort*)(ws + 524288);        // 128 KB
    ushort* hs   = (ushort*)(ws + 1048576);       // 134.2 MB bf16 [B*T, 256]
    if (ws_size < (size_t)135266304) return;      // ws too small -> recognizable absmax fail

    k_conv   <<<256, 256, 0, stream>>>(W1, W2, embed, W1b, W2b, Eb);
    k_proj   <<<256, 256, 0, stream>>>(embed, W_in, proj);
    k_recur  <<<128, 512, 0, stream>>>(idx, W, proj, hs);
    k_readout<<<2048, 512, 0, stream>>>(hs, W1b, W2b, Eb, b1, b2, gamma, beta, (float*)d_out);
}

// Round 4
// 2062.066 us; speedup vs baseline: 1.0000x; 1.0000x over previous
//
#include <hip/hip_runtime.h>
#include <cstdint>

typedef __attribute__((ext_vector_type(8))) short short8;
typedef __attribute__((ext_vector_type(4))) float f32x4;

__device__ __forceinline__ ushort f2bf(float x){
    uint32_t u = __float_as_uint(x);
    u = (u + 0x7FFFu + ((u >> 16) & 1u)) >> 16;
    return (ushort)u;
}

// ---------------- kernel 1: fp32 -> bf16 weight conversion ----------------
__global__ void k_conv(const float* __restrict__ W1, const float* __restrict__ W2,
                       const float* __restrict__ Emb,
                       ushort* __restrict__ W1b, ushort* __restrict__ W2b,
                       ushort* __restrict__ Eb){
    int i = blockIdx.x * 256 + threadIdx.x;   // grid 256 -> 65536
    W1b[i] = f2bf(W1[i]);
    W2b[i] = f2bf(W2[i]);
    Eb[i]  = f2bf(Emb[i]);
}

// -------- kernel 2: proj[v][h] = sum_e embed[v,e]*W_in[h,e]  (fp32) -------
__global__ void k_proj(const float* __restrict__ emb, const float* __restrict__ Win,
                       float* __restrict__ proj){
    __shared__ __align__(16) float se[256];
    int v = blockIdx.x, h = threadIdx.x;
    se[h] = emb[v*256 + h];
    __syncthreads();
    const float* wr = Win + h*256;
    float a0=0.f,a1=0.f,a2=0.f,a3=0.f;
    #pragma unroll
    for (int e = 0; e < 256; e += 4){
        float4 w = *(const float4*)(wr + e);
        a0 = fmaf(w.x, se[e+0], a0);
        a1 = fmaf(w.y, se[e+1], a1);
        a2 = fmaf(w.z, se[e+2], a2);
        a3 = fmaf(w.w, se[e+3], a3);
    }
    proj[v*256 + h] = (a0+a1)+(a2+a3);
}

// ---------------- kernel 3: ESN recurrence, fp32, W truly in VGPRs -------
// 128 blocks (one per batch row) x 512 threads (8 waves, 2/SIMD).
// thread t: c = t&7 (k-octant), rg = t>>3 (0..63); owns rows {4rg+q, q=0..3}
// x cols [32c, 32c+32). In-wave octet reduction via shfl_xor(1,2,4);
// lanes c<4 finalize row 4rg+c (distinct banks, contiguous hs store).
//
// KEY FIX vs rounds 1-3: W is staged global->LDS->VGPR. LDS loads cannot be
// marked invariant, the staging buffer is overwritten (reused as the s_h
// double buffer) and the t-loop contains a "memory"-clobber asm barrier, so
// the compiler CANNOT rematerialize the W loads inside the loop. Rounds 1-3
// re-streamed W from L2 every step (VGPR_Count=88 proved W never resided).
__global__ __launch_bounds__(512, 2) void k_recur(const int* __restrict__ idx,
        const float* __restrict__ W, const float* __restrict__ proj,
        ushort* __restrict__ hs){
    __shared__ __align__(16) float s_stage[32*256];  // 32 KB; reused as h dbuf
    __shared__ int s_idx[2048];
    const int tid = threadIdx.x;
    const int b   = blockIdx.x;
    const int c   = tid & 7;
    const int rg  = tid >> 3;

    for (int i = tid; i < 2048; i += 512) s_idx[i] = idx[b*2048 + i];

    // ---- stage W through LDS into VGPRs, 8 windows of 32 rows ----
    float4 w4[4][8];   // W[4rg+q][32c..32c+31], chunk j rotated by c
    const int myblk = rg >> 3;
    for (int blk = 0; blk < 8; ++blk){
        __syncthreads();
        const float4* src = (const float4*)(W + blk*32*256);
        float4* dst = (float4*)s_stage;
        #pragma unroll
        for (int i = 0; i < 4; ++i)
            dst[tid + i*512] = src[tid + i*512];
        __syncthreads();
        if (myblk == blk){
            #pragma unroll
            for (int q = 0; q < 4; ++q){
                const float* wr = s_stage + (4*(rg & 7) + q)*256 + c*32;
                #pragma unroll
                for (int j = 0; j < 8; ++j)
                    w4[q][j] = *(const float4*)(wr + 4*((j + c) & 7));
            }
        }
    }
    __syncthreads();
    if (tid < 256) s_stage[tid] = 0.f;     // h buffer (cur offset 0)
    __syncthreads();

    const int myrow = 4*rg + c;            // finalized row when c<4
    float h_prev = 0.f;
    ushort* hrow = hs + (size_t)b * 2048 * 256;
    int hoff = 0;                          // 0 / 256 double buffer
    for (int t = 0; t < 2048; ++t){
        int token = s_idx[t];
        float u = 0.f;
        if (c < 4) u = proj[token*256 + myrow];    // issued early, consumed late

        const float4* h4 = (const float4*)(s_stage + hoff + c*32);
        f32x4 a0 = {0.f,0.f,0.f,0.f}, a1 = a0, a2 = a0, a3 = a0;
        #pragma unroll
        for (int j = 0; j < 8; ++j){
            float4 hv = h4[(j + c) & 7];           // LDS addr runtime, regs static
            float4 w0 = w4[0][j], w1 = w4[1][j], w2 = w4[2][j], w3 = w4[3][j];
            a0[0]=fmaf(w0.x,hv.x,a0[0]); a0[1]=fmaf(w0.y,hv.y,a0[1]);
            a0[2]=fmaf(w0.z,hv.z,a0[2]); a0[3]=fmaf(w0.w,hv.w,a0[3]);
            a1[0]=fmaf(w1.x,hv.x,a1[0]); a1[1]=fmaf(w1.y,hv.y,a1[1]);
            a1[2]=fmaf(w1.z,hv.z,a1[2]); a1[3]=fmaf(w1.w,hv.w,a1[3]);
            a2[0]=fmaf(w2.x,hv.x,a2[0]); a2[1]=fmaf(w2.y,hv.y,a2[1]);
            a2[2]=fmaf(w2.z,hv.z,a2[2]); a2[3]=fmaf(w2.w,hv.w,a2[3]);
            a3[0]=fmaf(w3.x,hv.x,a3[0]); a3[1]=fmaf(w3.y,hv.y,a3[1]);
            a3[2]=fmaf(w3.z,hv.z,a3[2]); a3[3]=fmaf(w3.w,hv.w,a3[3]);
        }
        float s0 = (a0[0]+a0[1])+(a0[2]+a0[3]);
        float s1 = (a1[0]+a1[1])+(a1[2]+a1[3]);
        float s2 = (a2[0]+a2[1])+(a2[2]+a2[3]);
        float s3 = (a3[0]+a3[1])+(a3[2]+a3[3]);
        s0 += __shfl_xor(s0,1); s0 += __shfl_xor(s0,2); s0 += __shfl_xor(s0,4);
        s1 += __shfl_xor(s1,1); s1 += __shfl_xor(s1,2); s1 += __shfl_xor(s1,4);
        s2 += __shfl_xor(s2,1); s2 += __shfl_xor(s2,2); s2 += __shfl_xor(s2,4);
        s3 += __shfl_xor(s3,1); s3 += __shfl_xor(s3,2); s3 += __shfl_xor(s3,4);
        if (c < 4){
            float pre = (c==0 ? s0 : c==1 ? s1 : c==2 ? s2 : s3) + u;
            pre = fminf(20.f, fmaxf(-20.f, pre));
            float e  = __expf(2.f*pre);
            float th = 1.f - __fdividef(2.f, e + 1.f);
            float hn = 0.7f*h_prev + 0.3f*th;
            h_prev = hn;
            s_stage[(hoff ^ 256) + myrow] = hn;
            hrow[(size_t)t*256 + myrow] = f2bf(hn);
        }
        // LDS-only barrier: do NOT drain vmcnt (the hs store floats free).
        // The "memory" clobber also pins the staged-W LDS loads outside the loop.
        asm volatile("s_waitcnt lgkmcnt(0)\n\ts_barrier" ::: "memory");
        hoff ^= 256;
    }
}

// ---------------- kernel 4: fused readout MLP + LN + lm_head --------------
// per block: 128 rows of BT. 512 threads = 8 waves, wave owns 16 rows.
// GEMM1 (swapped, D[e,m]) -> gelu -> A1_lds[m][e]
// GEMM2 (swapped, D[e2,m]) -> LN over e2 -> y_lds[m][e2] (overwrites A1)
// GEMM3 (unswapped, D[m,v]) -> fp32 out
__global__ __launch_bounds__(512) void k_readout(
        const ushort* __restrict__ hs,
        const ushort* __restrict__ W1b, const ushort* __restrict__ W2b,
        const ushort* __restrict__ Eb,
        const float* __restrict__ b1, const float* __restrict__ b2,
        const float* __restrict__ gamma, const float* __restrict__ beta,
        float* __restrict__ out){
    __shared__ __align__(16) char w_lds[65536];   // staged weight half: 128 rows x 256 bf16
    __shared__ __align__(16) char a_lds[65536];   // A1 / y tile: 128 rows x 256 bf16

    const int tid  = threadIdx.x;
    const int wid  = tid >> 6;
    const int lane = tid & 63;
    const int lr   = lane & 15;
    const int lg   = lane >> 4;
    const size_t m0 = (size_t)blockIdx.x * 128;
    const int ml   = wid*16 + lr;                 // this lane's m-row (local)

    // stage a 128x256 bf16 weight half into w_lds, XOR-swizzled
    auto stage = [&](const ushort* src){
        #pragma unroll
        for (int i = 0; i < 8; ++i){
            int off = (i*512 + tid) * 16;
            uint4 v = *(const uint4*)((const char*)src + off);
            int row = off >> 9;
            *(uint4*)(w_lds + (off ^ ((row & 7) << 4))) = v;
        }
    };
    // A-fragment of staged weight, tile n, k-chunk k0
    auto wfrag = [&](int n, int k0) -> short8 {
        int row  = n*16 + lr;
        int addr = (row << 9) + k0*64 + lg*16;
        addr ^= (row & 7) << 4;
        return __builtin_bit_cast(short8, *(const uint4*)(w_lds + addr));
    };
    // fragment of a_lds at own m-row, k-chunk k0
    auto afrag = [&](int k0) -> short8 {
        int addr = (ml << 9) + k0*64 + lg*16;
        addr ^= (ml & 7) << 4;
        return __builtin_bit_cast(short8, *(const uint4*)(a_lds + addr));
    };
    // write 4 consecutive e-values (8B) into a_lds[ml][ecol..ecol+3]
    auto awrite = [&](int ecol, f32x4 v){
        ushort4 pk;
        pk.x = f2bf(v[0]); pk.y = f2bf(v[1]); pk.z = f2bf(v[2]); pk.w = f2bf(v[3]);
        int addr = (ml << 9) + ecol*2;
        addr ^= (ml & 7) << 4;
        *(ushort4*)(a_lds + addr) = pk;
    };

    // ---- hs fragments straight from global (16B/lane, reused both halves) ----
    short8 hb[8];
    {
        const char* p = (const char*)(hs + (m0 + ml)*256) + lg*16;
        #pragma unroll
        for (int k0 = 0; k0 < 8; ++k0)
            hb[k0] = __builtin_bit_cast(short8, *(const uint4*)(p + k0*64));
    }

    // ================= GEMM1: A1 = gelu(hs @ W1.T + b1) =================
    #pragma unroll
    for (int h = 0; h < 2; ++h){
        __syncthreads();
        stage(W1b + h*128*256);
        __syncthreads();
        #pragma unroll
        for (int n = 0; n < 8; ++n){
            int eb = h*128 + n*16;
            float4 bi = *(const float4*)(b1 + eb + lg*4);
            f32x4 acc = {bi.x, bi.y, bi.z, bi.w};
            #pragma unroll
            for (int k0 = 0; k0 < 8; ++k0)
                acc = __builtin_amdgcn_mfma_f32_16x16x32_bf16(wfrag(n,k0), hb[k0], acc, 0,0,0);
            f32x4 g;
            #pragma unroll
            for (int q = 0; q < 4; ++q){
                float x = acc[q];
                g[q] = 0.5f*x*(1.f + erff(x*0.70710678118654752440f));
            }
            awrite(eb + lg*4, g);
        }
    }

    // ================= GEMM2: o = A1 @ W2.T + b2 =================
    short8 ab[8];
    __syncthreads();
    #pragma unroll
    for (int k0 = 0; k0 < 8; ++k0) ab[k0] = afrag(k0);
    f32x4 oacc[16];
    #pragma unroll
    for (int h = 0; h < 2; ++h){
        __syncthreads();
        stage(W2b + h*128*256);
        __syncthreads();
        #pragma unroll
        for (int n = 0; n < 8; ++n){
            int eb = h*128 + n*16;
            float4 bi = *(const float4*)(b2 + eb + lg*4);
            f32x4 acc = {bi.x, bi.y, bi.z, bi.w};
            #pragma unroll
            for (int k0 = 0; k0 < 8; ++k0)
                acc = __builtin_amdgcn_mfma_f32_16x16x32_bf16(wfrag(n,k0), ab[k0], acc, 0,0,0);
            oacc[h*8+n] = acc;
        }
    }

    // ================= LayerNorm over e2 (row dim of swapped D2) =================
    {
        float sum = 0.f, ss = 0.f;
        #pragma unroll
        for (int i = 0; i < 16; ++i){
            #pragma unroll
            for (int q = 0; q < 4; ++q){ float x = oacc[i][q]; sum += x; ss += x*x; }
        }
        sum += __shfl_xor(sum, 16); ss += __shfl_xor(ss, 16);
        sum += __shfl_xor(sum, 32); ss += __shfl_xor(ss, 32);
        float mu   = sum * (1.f/256.f);
        float var  = ss * (1.f/256.f) - mu*mu;
        float rstd = rsqrtf(var + 1e-5f);
        #pragma unroll
        for (int i = 0; i < 16; ++i){
            int ecol = (i >> 3)*128 + (i & 7)*16 + lg*4;
            float4 g4 = *(const float4*)(gamma + ecol);
            float4 t4 = *(const float4*)(beta + ecol);
            f32x4 y;
            y[0] = (oacc[i][0]-mu)*rstd*g4.x + t4.x;
            y[1] = (oacc[i][1]-mu)*rstd*g4.y + t4.y;
            y[2] = (oacc[i][2]-mu)*rstd*g4.z + t4.z;
            y[3] = (oacc[i][3]-mu)*rstd*g4.w + t4.w;
            awrite(ecol, y);
        }
    }

    // ================= GEMM3: logits = y @ embed.T (unswapped) =================
    __syncthreads();
    #pragma unroll
    for (int k0 = 0; k0 < 8; ++k0) ab[k0] = afrag(k0);   // y fragments
    #pragma unroll
    for (int h = 0; h < 2; ++h){
        __syncthreads();
        stage(Eb + h*128*256);
        __syncthreads();
        #pragma unroll
        for (int n = 0; n < 8; ++n){
            f32x4 acc = {0.f,0.f,0.f,0.f};
            #pragma unroll
            for (int k0 = 0; k0 < 8; ++k0)
                acc = __builtin_amdgcn_mfma_f32_16x16x32_bf16(ab[k0], wfrag(n,k0), acc, 0,0,0);
            int v = h*128 + n*16 + lr;
            float* op = out + (m0 + wid*16 + lg*4)*256 + v;
            op[0]   = acc[0];
            op[256] = acc[1];
            op[512] = acc[2];
            op[768] = acc[3];
        }
    }
}

// --------------------------------------------------------------------------
extern "C" void kernel_launch(void* const* d_in, const int* in_sizes, int n_in,
                              void* d_out, int out_size, void* d_ws, size_t ws_size,
                              hipStream_t stream){
    const int*   idx   = (const int*)d_in[0];
    const float* embed = (const float*)d_in[1];
    const float* W_in  = (const float*)d_in[2];
    const float* W     = (const float*)d_in[3];
    const float* W1    = (const float*)d_in[4];
    const float* b1    = (const float*)d_in[5];
    const float* W2    = (const float*)d_in[6];
    const float* b2    = (const float*)d_in[7];
    const float* gamma = (const float*)d_in[8];
    const float* beta  = (const float*)d_in[9];

    char* ws = (char*)d_ws;
    float*  proj = (float*)ws;                    // 256 KB fp32
    ushort* W1b  = (ushort*)(ws + 262144);        // 128 KB bf16
    ushort* W2b  = (ushort*)(ws + 393216);        // 128 KB
    ushort* Eb   = (ushort*)(ws + 524288);        // 128 KB
    ushort* hs   = (ushort*)(ws + 1048576);       // 134.2 MB bf16 [B*T, 256]
    if (ws_size < (size_t)135266304) return;      // ws too small -> recognizable absmax fail

    k_conv   <<<256, 256, 0, stream>>>(W1, W2, embed, W1b, W2b, Eb);
    k_proj   <<<256, 256, 0, stream>>>(embed, W_in, proj);
    k_recur  <<<128, 512, 0, stream>>>(idx, W, proj, hs);
    k_readout<<<2048, 512, 0, stream>>>(hs, W1b, W2b, Eb, b1, b2, gamma, beta, (float*)d_out);
}

// Round 5
// 1456.293 us; speedup vs baseline: 1.4160x; 1.4160x over previous
//
#include <hip/hip_runtime.h>
#include <cstdint>

typedef __attribute__((ext_vector_type(8))) short short8;
typedef __attribute__((ext_vector_type(4))) float f32x4;

__device__ __forceinline__ ushort f2bf(float x){
    uint32_t u = __float_as_uint(x);
    u = (u + 0x7FFFu + ((u >> 16) & 1u)) >> 16;
    return (ushort)u;
}

// ---------------- kernel 1: fp32 -> bf16 weight conversion ----------------
__global__ void k_conv(const float* __restrict__ W1, const float* __restrict__ W2,
                       const float* __restrict__ Emb,
                       ushort* __restrict__ W1b, ushort* __restrict__ W2b,
                       ushort* __restrict__ Eb){
    int i = blockIdx.x * 256 + threadIdx.x;   // grid 256 -> 65536
    W1b[i] = f2bf(W1[i]);
    W2b[i] = f2bf(W2[i]);
    Eb[i]  = f2bf(Emb[i]);
}

// -------- kernel 2: proj[v][h] = sum_e embed[v,e]*W_in[h,e]  (fp32) -------
__global__ void k_proj(const float* __restrict__ emb, const float* __restrict__ Win,
                       float* __restrict__ proj){
    __shared__ __align__(16) float se[256];
    int v = blockIdx.x, h = threadIdx.x;
    se[h] = emb[v*256 + h];
    __syncthreads();
    const float* wr = Win + h*256;
    float a0=0.f,a1=0.f,a2=0.f,a3=0.f;
    #pragma unroll
    for (int e = 0; e < 256; e += 4){
        float4 w = *(const float4*)(wr + e);
        a0 = fmaf(w.x, se[e+0], a0);
        a1 = fmaf(w.y, se[e+1], a1);
        a2 = fmaf(w.z, se[e+2], a2);
        a3 = fmaf(w.w, se[e+3], a3);
    }
    proj[v*256 + h] = (a0+a1)+(a2+a3);
}

// -------- kernel 2b: CSR build. W is ~90% sparse (~25.6 nz/row). ---------
// 256 blocks x 64 threads: block r compacts row r via ballot prefix-sum.
// ccol stores BYTE offsets (col*4). Rows padded to 56 with val=0,col=0
// (0 * h[0] is a harmless FMA).
__global__ void k_csr(const float* __restrict__ W, float* __restrict__ cval,
                      int* __restrict__ ccol, int* __restrict__ cnt){
    const int r = blockIdx.x, lane = threadIdx.x;   // 64 lanes
    int base = 0;
    for (int c = 0; c < 4; ++c){
        float w = W[r*256 + c*64 + lane];
        unsigned long long m = __ballot(w != 0.f);
        int pos = __popcll(m & ((1ull << lane) - 1ull));
        if (w != 0.f){
            int p = base + pos;
            if (p < 56){ cval[r*56 + p] = w; ccol[r*56 + p] = (c*64 + lane)*4; }
        }
        base += __popcll(m);
    }
    if (base > 56) base = 56;                       // P ~ 1e-10, safety clamp
    if (lane == 0) cnt[r] = base;
    for (int p = base + lane; p < 56; p += 64){ cval[r*56+p] = 0.f; ccol[r*56+p] = 0; }
}

// -------- kernel 2c: count-sort rows so waves get uniform nnz ------------
__global__ void k_rank(const int* __restrict__ cnt, int* __restrict__ sperm){
    __shared__ int sc[256];
    int i = threadIdx.x;
    sc[i] = cnt[i];
    __syncthreads();
    int ci = sc[i], r = 0;
    for (int j = 0; j < 256; ++j){
        int cj = sc[j];
        r += (cj < ci) || (cj == ci && j < i);
    }
    sperm[r] = i;
}

// ---------------- kernel 3: ESN recurrence, SPARSE W in registers --------
// 128 blocks (one per batch row) x 512 threads (2 threads per h-row).
// thread t: g = t>>1 (sorted slot), sub = t&1; row = sperm[g]; owns nz
// entries n = sub, sub+2, ... of its row's CSR list (~13 each, regs).
// Per step: gather h[col] from LDS + fmac; one shfl_xor(1) combines the
// two halves; sub==0 finalizes (u add, clip, tanh, leak) and writes h.
// Loop bound KW is wave-uniform (rows count-sorted + readfirstlane) ->
// scalar-branch chunked early exit, register arrays stay static-indexed.
// No __restrict__ on csr/proj pointers (hs stores may alias -> remat of the
// csr loads into the loop is illegal) + in-loop empty-asm pin.
__global__ __launch_bounds__(512) void k_recur(const int* __restrict__ idx,
        const float* cval, const int* ccol, const int* cnt, const int* sperm,
        const float* proj, ushort* hs){
    __shared__ __align__(16) float s_h[2][256];
    __shared__ int s_idx[2048];
    const int tid = threadIdx.x;
    const int b   = blockIdx.x;
    const int sub = tid & 1;
    const int g   = tid >> 1;

    for (int i = tid; i < 2048; i += 512) s_idx[i] = idx[b*2048 + i];

    const int myrow = sperm[g];
    const int mycnt = cnt[myrow];
    float val[28]; int colb[28];
    #pragma unroll
    for (int k = 0; k < 28; ++k){
        int n = sub + 2*k;
        val[k]  = cval[myrow*56 + n];
        colb[k] = ccol[myrow*56 + n];
    }
    int kw = (mycnt + 1 - sub) >> 1;               // my entry count
    kw = max(kw, __shfl_xor(kw, 1));  kw = max(kw, __shfl_xor(kw, 2));
    kw = max(kw, __shfl_xor(kw, 4));  kw = max(kw, __shfl_xor(kw, 8));
    kw = max(kw, __shfl_xor(kw, 16)); kw = max(kw, __shfl_xor(kw, 32));
    const int KW = __builtin_amdgcn_readfirstlane(kw);

    if (tid < 256) s_h[0][tid] = 0.f;
    __syncthreads();

    float h_prev = 0.f;
    ushort* hrow = hs + (size_t)b * 2048 * 256;
    int hoff = 0;
    for (int t = 0; t < 2048; ++t){
        // pin CSR registers: redefine per-iteration so they can't be
        // spilled-and-reloaded cheaply or rematerialized (rounds 2-4 bug)
        asm volatile("" : "+v"(val[0]),"+v"(val[1]),"+v"(val[2]),"+v"(val[3]),
                          "+v"(val[4]),"+v"(val[5]),"+v"(val[6]),"+v"(val[7]),
                          "+v"(val[8]),"+v"(val[9]),"+v"(val[10]),"+v"(val[11]),
                          "+v"(val[12]),"+v"(val[13]),"+v"(val[14]),"+v"(val[15]),
                          "+v"(val[16]),"+v"(val[17]),"+v"(val[18]),"+v"(val[19]),
                          "+v"(val[20]),"+v"(val[21]),"+v"(val[22]),"+v"(val[23]),
                          "+v"(val[24]),"+v"(val[25]),"+v"(val[26]),"+v"(val[27]));
        asm volatile("" : "+v"(colb[0]),"+v"(colb[1]),"+v"(colb[2]),"+v"(colb[3]),
                          "+v"(colb[4]),"+v"(colb[5]),"+v"(colb[6]),"+v"(colb[7]),
                          "+v"(colb[8]),"+v"(colb[9]),"+v"(colb[10]),"+v"(colb[11]),
                          "+v"(colb[12]),"+v"(colb[13]),"+v"(colb[14]),"+v"(colb[15]),
                          "+v"(colb[16]),"+v"(colb[17]),"+v"(colb[18]),"+v"(colb[19]),
                          "+v"(colb[20]),"+v"(colb[21]),"+v"(colb[22]),"+v"(colb[23]),
                          "+v"(colb[24]),"+v"(colb[25]),"+v"(colb[26]),"+v"(colb[27]));

        int token = s_idx[t];
        float u = 0.f;
        if (sub == 0) u = proj[token*256 + myrow];   // issued early, used late

        const char* hb = (const char*)&s_h[hoff][0];
        float acc = 0.f;
        #pragma unroll
        for (int kc = 0; kc < 7; ++kc){
            if (kc*4 >= KW) break;                   // scalar branch (KW in SGPR)
            #pragma unroll
            for (int j2 = 0; j2 < 4; ++j2){
                int k = kc*4 + j2;
                acc = fmaf(val[k], *(const float*)(hb + colb[k]), acc);
            }
        }
        acc += __shfl_xor(acc, 1);
        float pre = acc + u;
        pre = fminf(20.f, fmaxf(-20.f, pre));
        float e  = __expf(2.f*pre);
        float th = 1.f - __fdividef(2.f, e + 1.f);
        float hn = 0.7f*h_prev + 0.3f*th;
        if (sub == 0){
            h_prev = hn;
            s_h[hoff^1][myrow] = hn;
            hrow[(size_t)t*256 + myrow] = f2bf(hn);
        }
        // LDS-only barrier: do NOT drain vmcnt (hs store floats free)
        asm volatile("s_waitcnt lgkmcnt(0)\n\ts_barrier" ::: "memory");
        hoff ^= 1;
    }
}

// ---------------- kernel 4: fused readout MLP + LN + lm_head --------------
// per block: 128 rows of BT. 512 threads = 8 waves, wave owns 16 rows.
// GEMM1 (swapped, D[e,m]) -> gelu -> A1_lds[m][e]
// GEMM2 (swapped, D[e2,m]) -> LN over e2 -> y_lds[m][e2] (overwrites A1)
// GEMM3 (unswapped, D[m,v]) -> fp32 out
__global__ __launch_bounds__(512) void k_readout(
        const ushort* __restrict__ hs,
        const ushort* __restrict__ W1b, const ushort* __restrict__ W2b,
        const ushort* __restrict__ Eb,
        const float* __restrict__ b1, const float* __restrict__ b2,
        const float* __restrict__ gamma, const float* __restrict__ beta,
        float* __restrict__ out){
    __shared__ __align__(16) char w_lds[65536];   // staged weight half: 128 rows x 256 bf16
    __shared__ __align__(16) char a_lds[65536];   // A1 / y tile: 128 rows x 256 bf16

    const int tid  = threadIdx.x;
    const int wid  = tid >> 6;
    const int lane = tid & 63;
    const int lr   = lane & 15;
    const int lg   = lane >> 4;
    const size_t m0 = (size_t)blockIdx.x * 128;
    const int ml   = wid*16 + lr;                 // this lane's m-row (local)

    // stage a 128x256 bf16 weight half into w_lds, XOR-swizzled
    auto stage = [&](const ushort* src){
        #pragma unroll
        for (int i = 0; i < 8; ++i){
            int off = (i*512 + tid) * 16;
            uint4 v = *(const uint4*)((const char*)src + off);
            int row = off >> 9;
            *(uint4*)(w_lds + (off ^ ((row & 7) << 4))) = v;
        }
    };
    // A-fragment of staged weight, tile n, k-chunk k0
    auto wfrag = [&](int n, int k0) -> short8 {
        int row  = n*16 + lr;
        int addr = (row << 9) + k0*64 + lg*16;
        addr ^= (row & 7) << 4;
        return __builtin_bit_cast(short8, *(const uint4*)(w_lds + addr));
    };
    // fragment of a_lds at own m-row, k-chunk k0
    auto afrag = [&](int k0) -> short8 {
        int addr = (ml << 9) + k0*64 + lg*16;
        addr ^= (ml & 7) << 4;
        return __builtin_bit_cast(short8, *(const uint4*)(a_lds + addr));
    };
    // write 4 consecutive e-values (8B) into a_lds[ml][ecol..ecol+3]
    auto awrite = [&](int ecol, f32x4 v){
        ushort4 pk;
        pk.x = f2bf(v[0]); pk.y = f2bf(v[1]); pk.z = f2bf(v[2]); pk.w = f2bf(v[3]);
        int addr = (ml << 9) + ecol*2;
        addr ^= (ml & 7) << 4;
        *(ushort4*)(a_lds + addr) = pk;
    };

    // ---- hs fragments straight from global (16B/lane, reused both halves) ----
    short8 hb[8];
    {
        const char* p = (const char*)(hs + (m0 + ml)*256) + lg*16;
        #pragma unroll
        for (int k0 = 0; k0 < 8; ++k0)
            hb[k0] = __builtin_bit_cast(short8, *(const uint4*)(p + k0*64));
    }

    // ================= GEMM1: A1 = gelu(hs @ W1.T + b1) =================
    #pragma unroll
    for (int h = 0; h < 2; ++h){
        __syncthreads();
        stage(W1b + h*128*256);
        __syncthreads();
        #pragma unroll
        for (int n = 0; n < 8; ++n){
            int eb = h*128 + n*16;
            float4 bi = *(const float4*)(b1 + eb + lg*4);
            f32x4 acc = {bi.x, bi.y, bi.z, bi.w};
            #pragma unroll
            for (int k0 = 0; k0 < 8; ++k0)
                acc = __builtin_amdgcn_mfma_f32_16x16x32_bf16(wfrag(n,k0), hb[k0], acc, 0,0,0);
            f32x4 g;
            #pragma unroll
            for (int q = 0; q < 4; ++q){
                float x = acc[q];
                g[q] = 0.5f*x*(1.f + erff(x*0.70710678118654752440f));
            }
            awrite(eb + lg*4, g);
        }
    }

    // ================= GEMM2: o = A1 @ W2.T + b2 =================
    short8 ab[8];
    __syncthreads();
    #pragma unroll
    for (int k0 = 0; k0 < 8; ++k0) ab[k0] = afrag(k0);
    f32x4 oacc[16];
    #pragma unroll
    for (int h = 0; h < 2; ++h){
        __syncthreads();
        stage(W2b + h*128*256);
        __syncthreads();
        #pragma unroll
        for (int n = 0; n < 8; ++n){
            int eb = h*128 + n*16;
            float4 bi = *(const float4*)(b2 + eb + lg*4);
            f32x4 acc = {bi.x, bi.y, bi.z, bi.w};
            #pragma unroll
            for (int k0 = 0; k0 < 8; ++k0)
                acc = __builtin_amdgcn_mfma_f32_16x16x32_bf16(wfrag(n,k0), ab[k0], acc, 0,0,0);
            oacc[h*8+n] = acc;
        }
    }

    // ================= LayerNorm over e2 (row dim of swapped D2) =================
    {
        float sum = 0.f, ss = 0.f;
        #pragma unroll
        for (int i = 0; i < 16; ++i){
            #pragma unroll
            for (int q = 0; q < 4; ++q){ float x = oacc[i][q]; sum += x; ss += x*x; }
        }
        sum += __shfl_xor(sum, 16); ss += __shfl_xor(ss, 16);
        sum += __shfl_xor(sum, 32); ss += __shfl_xor(ss, 32);
        float mu   = sum * (1.f/256.f);
        float var  = ss * (1.f/256.f) - mu*mu;
        float rstd = rsqrtf(var + 1e-5f);
        #pragma unroll
        for (int i = 0; i < 16; ++i){
            int ecol = (i >> 3)*128 + (i & 7)*16 + lg*4;
            float4 g4 = *(const float4*)(gamma + ecol);
            float4 t4 = *(const float4*)(beta + ecol);
            f32x4 y;
            y[0] = (oacc[i][0]-mu)*rstd*g4.x + t4.x;
            y[1] = (oacc[i][1]-mu)*rstd*g4.y + t4.y;
            y[2] = (oacc[i][2]-mu)*rstd*g4.z + t4.z;
            y[3] = (oacc[i][3]-mu)*rstd*g4.w + t4.w;
            awrite(ecol, y);
        }
    }

    // ================= GEMM3: logits = y @ embed.T (unswapped) =================
    __syncthreads();
    #pragma unroll
    for (int k0 = 0; k0 < 8; ++k0) ab[k0] = afrag(k0);   // y fragments
    #pragma unroll
    for (int h = 0; h < 2; ++h){
        __syncthreads();
        stage(Eb + h*128*256);
        __syncthreads();
        #pragma unroll
        for (int n = 0; n < 8; ++n){
            f32x4 acc = {0.f,0.f,0.f,0.f};
            #pragma unroll
            for (int k0 = 0; k0 < 8; ++k0)
                acc = __builtin_amdgcn_mfma_f32_16x16x32_bf16(ab[k0], wfrag(n,k0), acc, 0,0,0);
            int v = h*128 + n*16 + lr;
            float* op = out + (m0 + wid*16 + lg*4)*256 + v;
            op[0]   = acc[0];
            op[256] = acc[1];
            op[512] = acc[2];
            op[768] = acc[3];
        }
    }
}

// --------------------------------------------------------------------------
extern "C" void kernel_launch(void* const* d_in, const int* in_sizes, int n_in,
                              void* d_out, int out_size, void* d_ws, size_t ws_size,
                              hipStream_t stream){
    const int*   idx   = (const int*)d_in[0];
    const float* embed = (const float*)d_in[1];
    const float* W_in  = (const float*)d_in[2];
    const float* W     = (const float*)d_in[3];
    const float* W1    = (const float*)d_in[4];
    const float* b1    = (const float*)d_in[5];
    const float* W2    = (const float*)d_in[6];
    const float* b2    = (const float*)d_in[7];
    const float* gamma = (const float*)d_in[8];
    const float* beta  = (const float*)d_in[9];

    char* ws = (char*)d_ws;
    float*  proj = (float*)ws;                    // 256 KB fp32
    ushort* W1b  = (ushort*)(ws + 262144);        // 128 KB bf16
    ushort* W2b  = (ushort*)(ws + 393216);        // 128 KB
    ushort* Eb   = (ushort*)(ws + 524288);        // 128 KB
    float*  cval = (float*)(ws + 655360);         // 256*56 f32 = 56 KB
    int*    ccol = (int*)(ws + 712704);           // 256*56 i32 = 56 KB
    int*    cnt  = (int*)(ws + 770048);           // 1 KB
    int*    sperm= (int*)(ws + 771072);           // 1 KB
    ushort* hs   = (ushort*)(ws + 1048576);       // 134.2 MB bf16 [B*T, 256]
    if (ws_size < (size_t)135266304) return;      // ws too small -> recognizable absmax fail

    k_conv   <<<256, 256, 0, stream>>>(W1, W2, embed, W1b, W2b, Eb);
    k_proj   <<<256, 256, 0, stream>>>(embed, W_in, proj);
    k_csr    <<<256, 64, 0, stream>>>(W, cval, ccol, cnt);
    k_rank   <<<1, 256, 0, stream>>>(cnt, sperm);
    k_recur  <<<128, 512, 0, stream>>>(idx, cval, ccol, cnt, sperm, proj, hs);
    k_readout<<<2048, 512, 0, stream>>>(hs, W1b, W2b, Eb, b1, b2, gamma, beta, (float*)d_out);
}